// Round 1
// baseline (431.627 us; speedup 1.0000x reference)
//
#include <hip/hip_runtime.h>

#define N_NODES 100000
#define N_EDGES 1600000
#define FEATS 64

// Kernel 1: edge scatter-add. One wave (64 lanes) per edge; lane l handles
// feature l. feat[src*64+l] is a coalesced 256B read, atomicAdd to
// agg[dst*64+l] is a coalesced 256B RMW. src/dst loads are wave-uniform.
__global__ void gcn_scatter(const float* __restrict__ feat,
                            const int* __restrict__ src,
                            const int* __restrict__ dst,
                            float* __restrict__ agg) {
    int e = blockIdx.x * (blockDim.x >> 6) + (threadIdx.x >> 6);
    int lane = threadIdx.x & 63;
    if (e < N_EDGES) {
        int s = src[e];
        int d = dst[e];
        atomicAdd(&agg[d * FEATS + lane], feat[s * FEATS + lane]);
    }
}

// Kernel 2: h = relu(agg @ W^T + b). W is [out,in]=[64,64].
// 256 threads/block = 4 rows; thread computes out[row][o], o = tid&63.
// W staged in LDS padded to 65 cols: lane l reads Ws[l][i] -> bank (l+i)%32,
// 2 lanes/bank = conflict-free (free on CDNA4).
__global__ void gcn_linear(const float* __restrict__ agg,
                           const float* __restrict__ W,
                           const float* __restrict__ b,
                           float* __restrict__ out) {
    __shared__ float Ws[64][65];
    int tid = threadIdx.x;
    for (int i = tid; i < 64 * 64; i += 256)
        Ws[i >> 6][i & 63] = W[i];
    __syncthreads();

    int row = blockIdx.x * 4 + (tid >> 6);
    int o = tid & 63;
    if (row < N_NODES) {
        const float* a = &agg[row * FEATS];
        float sum = b[o];
#pragma unroll
        for (int i = 0; i < FEATS; ++i)
            sum += a[i] * Ws[o][i];
        out[row * FEATS + o] = fmaxf(sum, 0.0f);
    }
}

extern "C" void kernel_launch(void* const* d_in, const int* in_sizes, int n_in,
                              void* d_out, int out_size, void* d_ws, size_t ws_size,
                              hipStream_t stream) {
    const float* features = (const float*)d_in[0];
    const int*   src      = (const int*)d_in[1];
    const int*   dst      = (const int*)d_in[2];
    const float* W        = (const float*)d_in[3];
    const float* b        = (const float*)d_in[4];
    float* out = (float*)d_out;
    float* agg = (float*)d_ws;  // N_NODES*FEATS floats = 25.6 MB scratch

    // Zero the aggregation buffer every call (d_ws is not re-poisoned/zeroed
    // between timed replays). hipMemsetAsync is graph-capture-safe.
    hipMemsetAsync(agg, 0, (size_t)N_NODES * FEATS * sizeof(float), stream);

    // Scatter: 4 edges per 256-thread block.
    int edges_per_block = 256 / 64;
    int nblk = (N_EDGES + edges_per_block - 1) / edges_per_block;
    gcn_scatter<<<nblk, 256, 0, stream>>>(features, src, dst, agg);

    // Linear+ReLU: 4 rows per 256-thread block.
    int nblk2 = (N_NODES + 3) / 4;
    gcn_linear<<<nblk2, 256, 0, stream>>>(agg, W, b, out);
}

// Round 2
// 298.453 us; speedup vs baseline: 1.4462x; 1.4462x over previous
//
#include <hip/hip_runtime.h>

#define N_NODES 100000
#define N_EDGES 1600000
#define FEATS 64

#define SCAN_B 1024
#define N_SCAN_BLOCKS ((N_NODES + SCAN_B - 1) / SCAN_B)  // 98

// ---- CSR build ----

__global__ void gcn_hist(const int* __restrict__ dst, int* __restrict__ deg) {
    int i = blockIdx.x * blockDim.x + threadIdx.x;
    if (i < N_EDGES) atomicAdd(&deg[dst[i]], 1);
}

// Per-block exclusive scan (Hillis-Steele in LDS) + block totals.
__global__ void gcn_scan_local(const int* __restrict__ deg, int* __restrict__ offs,
                               int* __restrict__ bsums) {
    __shared__ int tmp[SCAN_B];
    int gid = blockIdx.x * SCAN_B + threadIdx.x;
    int v = (gid < N_NODES) ? deg[gid] : 0;
    tmp[threadIdx.x] = v;
    __syncthreads();
    for (int off = 1; off < SCAN_B; off <<= 1) {
        int t = (threadIdx.x >= off) ? tmp[threadIdx.x - off] : 0;
        __syncthreads();
        tmp[threadIdx.x] += t;
        __syncthreads();
    }
    if (gid < N_NODES) offs[gid] = tmp[threadIdx.x] - v;  // exclusive within block
    if (threadIdx.x == SCAN_B - 1) bsums[blockIdx.x] = tmp[threadIdx.x];
}

// Tiny: exclusive-scan the 98 block sums serially.
__global__ void gcn_scan_bsums(int* __restrict__ bsums) {
    if (threadIdx.x == 0) {
        int run = 0;
        for (int i = 0; i < N_SCAN_BLOCKS; ++i) { int t = bsums[i]; bsums[i] = run; run += t; }
    }
}

__global__ void gcn_scan_add(int* __restrict__ offs, const int* __restrict__ bsums,
                             int* __restrict__ cursor) {
    int gid = blockIdx.x * SCAN_B + threadIdx.x;
    if (gid < N_NODES) {
        int o = offs[gid] + bsums[blockIdx.x];
        offs[gid] = o;
        cursor[gid] = o;  // cursor starts at segment base
    }
}

// Bucket-fill: store the SOURCE id directly (saves an indirection in the
// gather). Slot order within a segment is race-determined; sum order
// nondeterminism is ~1e-6, far under threshold.
__global__ void gcn_fill(const int* __restrict__ src, const int* __restrict__ dst,
                         int* __restrict__ cursor, int* __restrict__ csr_src) {
    int i = blockIdx.x * blockDim.x + threadIdx.x;
    if (i < N_EDGES) {
        int slot = atomicAdd(&cursor[dst[i]], 1);
        csr_src[slot] = src[i];
    }
}

// ---- fused gather-sum + linear + relu ----
// One wave per node; lane l owns feature l. Register accumulation (no float
// atomics, no global agg buffer). Then LDS row buffer + W[64][65] for the
// 64x64 linear; Ws[l][i] -> bank (l+i)%32, 2 lanes/bank = free.
__global__ __launch_bounds__(256) void gcn_gather_linear(
    const float* __restrict__ feat, const int* __restrict__ offs,
    const int* __restrict__ deg, const int* __restrict__ csr_src,
    const float* __restrict__ W, const float* __restrict__ b,
    float* __restrict__ out) {
    __shared__ float Ws[64][65];
    __shared__ float rowbuf[4][64];
    int tid = threadIdx.x;
    for (int i = tid; i < 64 * 64; i += 256)
        Ws[i >> 6][i & 63] = W[i];

    int wv = tid >> 6, lane = tid & 63;
    int node = blockIdx.x * 4 + wv;
    float acc = 0.0f;
    if (node < N_NODES) {
        int start = offs[node];
        int d = deg[node];
        for (int base = 0; base < d; base += 64) {
            int cnt = min(64, d - base);
            int s = (base + lane < d) ? csr_src[start + base + lane] : 0;
            int j = 0;
            for (; j + 4 <= cnt; j += 4) {  // 4-deep MLP
                int s0 = __shfl(s, j), s1 = __shfl(s, j + 1);
                int s2 = __shfl(s, j + 2), s3 = __shfl(s, j + 3);
                float f0 = feat[s0 * FEATS + lane];
                float f1 = feat[s1 * FEATS + lane];
                float f2 = feat[s2 * FEATS + lane];
                float f3 = feat[s3 * FEATS + lane];
                acc += f0; acc += f1; acc += f2; acc += f3;
            }
            for (; j < cnt; ++j) {
                int sj = __shfl(s, j);
                acc += feat[sj * FEATS + lane];
            }
        }
    }
    rowbuf[wv][lane] = acc;
    __syncthreads();  // covers Ws staging too
    if (node < N_NODES) {
        float sum = b[lane];
#pragma unroll
        for (int i = 0; i < FEATS; ++i)
            sum += Ws[lane][i] * rowbuf[wv][i];  // rowbuf read is broadcast
        out[node * FEATS + lane] = fmaxf(sum, 0.0f);
    }
}

extern "C" void kernel_launch(void* const* d_in, const int* in_sizes, int n_in,
                              void* d_out, int out_size, void* d_ws, size_t ws_size,
                              hipStream_t stream) {
    const float* features = (const float*)d_in[0];
    const int*   src      = (const int*)d_in[1];
    const int*   dst      = (const int*)d_in[2];
    const float* W        = (const float*)d_in[3];
    const float* b        = (const float*)d_in[4];
    float* out = (float*)d_out;

    // Workspace layout (ints): deg | offs | cursor | bsums | csr_src  (~7.6 MB)
    int* ws   = (int*)d_ws;
    int* deg    = ws;
    int* offs   = ws + 100000;
    int* cursor = ws + 200000;
    int* bsums  = ws + 300000;
    int* csr    = ws + 301024;

    hipMemsetAsync(deg, 0, (size_t)N_NODES * sizeof(int), stream);

    gcn_hist<<<(N_EDGES + 255) / 256, 256, 0, stream>>>(dst, deg);
    gcn_scan_local<<<N_SCAN_BLOCKS, SCAN_B, 0, stream>>>(deg, offs, bsums);
    gcn_scan_bsums<<<1, 64, 0, stream>>>(bsums);
    gcn_scan_add<<<N_SCAN_BLOCKS, SCAN_B, 0, stream>>>(offs, bsums, cursor);
    gcn_fill<<<(N_EDGES + 255) / 256, 256, 0, stream>>>(src, dst, cursor, csr);

    gcn_gather_linear<<<(N_NODES + 3) / 4, 256, 0, stream>>>(
        features, offs, deg, csr, W, b, out);
}

// Round 5
// 251.899 us; speedup vs baseline: 1.7135x; 1.1848x over previous
//
#include <hip/hip_runtime.h>

#define N_NODES 100000
#define N_EDGES 1600000
#define FEATS 64

#define NPART 8
#define NPP 12500            // nodes per partition (8*12500 = 100000 exactly)
#define EPB 2048             // edges scanned per block chunk
#define NCHUNK ((N_EDGES + EPB - 1) / EPB)   // 782

#define SCAN_B 1024
#define N_SCAN_BLOCKS ((N_NODES + SCAN_B - 1) / SCAN_B)  // 98

static __device__ __forceinline__ unsigned short f2bf(float f) {
    unsigned int u = __float_as_uint(f);
    unsigned int r = (u + 0x7fffu + ((u >> 16) & 1u)) >> 16;  // RNE
    return (unsigned short)r;
}

// Convert feature table to bf16 (halves gather traffic; 12.8 MB table).
__global__ void gcn_tobf16(const float* __restrict__ f, ushort4* __restrict__ o) {
    int i = blockIdx.x * blockDim.x + threadIdx.x;
    if (i < (N_NODES * FEATS) / 4) {
        float4 v = ((const float4*)f)[i];
        ushort4 r;
        r.x = f2bf(v.x); r.y = f2bf(v.y); r.z = f2bf(v.z); r.w = f2bf(v.w);
        o[i] = r;
    }
}

// XCD-partitioned histogram: partition p = blockIdx&7 only counts dsts in its
// node range, so each deg cache line is owned by one partition (-> one XCD
// under round-robin placement; correctness independent of placement).
__global__ void gcn_hist(const int* __restrict__ dst, int* __restrict__ deg) {
    int part = blockIdx.x & (NPART - 1);
    int cb = (blockIdx.x >> 3) * EPB;
    int lo = part * NPP;
    for (int it = 0; it < EPB; it += 256) {
        int i = cb + it + threadIdx.x;
        if (i < N_EDGES) {
            unsigned int d = (unsigned int)(dst[i] - lo);
            if (d < NPP) atomicAdd(&deg[lo + d], 1);
        }
    }
}

// Per-block exclusive scan (Hillis-Steele in LDS) + block totals.
__global__ void gcn_scan_local(const int* __restrict__ deg, int* __restrict__ offs,
                               int* __restrict__ bsums) {
    __shared__ int tmp[SCAN_B];
    int gid = blockIdx.x * SCAN_B + threadIdx.x;
    int v = (gid < N_NODES) ? deg[gid] : 0;
    tmp[threadIdx.x] = v;
    __syncthreads();
    for (int off = 1; off < SCAN_B; off <<= 1) {
        int t = (threadIdx.x >= off) ? tmp[threadIdx.x - off] : 0;
        __syncthreads();
        tmp[threadIdx.x] += t;
        __syncthreads();
    }
    if (gid < N_NODES) offs[gid] = tmp[threadIdx.x] - v;
    if (threadIdx.x == SCAN_B - 1) bsums[blockIdx.x] = tmp[threadIdx.x];
}

// Wave-parallel exclusive scan of the 98 block sums (was a serial 1-thread
// loop = ~98 dependent global round-trips).
__global__ void gcn_scan_bsums(int* __restrict__ bsums) {
    int l = threadIdx.x;  // 64 lanes, 2 elems/lane
    int a = 0, b = 0;
    if (2 * l < N_SCAN_BLOCKS)     a = bsums[2 * l];
    if (2 * l + 1 < N_SCAN_BLOCKS) b = bsums[2 * l + 1];
    int s = a + b;
    for (int off = 1; off < 64; off <<= 1) {
        int t = __shfl_up(s, off);
        if (l >= off) s += t;
    }
    int excl = s - (a + b);
    if (2 * l < N_SCAN_BLOCKS)     bsums[2 * l] = excl;
    if (2 * l + 1 < N_SCAN_BLOCKS) bsums[2 * l + 1] = excl + a;
}

__global__ void gcn_scan_add(int* __restrict__ offs, const int* __restrict__ bsums,
                             int* __restrict__ cursor) {
    int gid = blockIdx.x * SCAN_B + threadIdx.x;
    if (gid < N_NODES) {
        int o = offs[gid] + bsums[blockIdx.x];
        offs[gid] = o;
        cursor[gid] = o;
    }
}

// XCD-partitioned bucket fill: each partition's csr region (~800 KB) is only
// written by its own blocks -> L2-resident, no cross-XCD line false sharing.
__global__ void gcn_fill(const int* __restrict__ src, const int* __restrict__ dst,
                         int* __restrict__ cursor, int* __restrict__ csr) {
    int part = blockIdx.x & (NPART - 1);
    int cb = (blockIdx.x >> 3) * EPB;
    int lo = part * NPP;
    for (int it = 0; it < EPB; it += 256) {
        int i = cb + it + threadIdx.x;
        if (i < N_EDGES) {
            int d = dst[i];
            int s = src[i];
            if ((unsigned int)(d - lo) < NPP) {
                int slot = atomicAdd(&cursor[d], 1);
                csr[slot] = s;
            }
        }
    }
}

// Fused gather-sum + linear + relu. One wave per node. bf16 feature table:
// 32 lanes x u32 (2 feats) per edge, wave processes 2 edges per step
// (lane>>5 selects which edge), shfl_xor(32) cross-adds the halves.
__global__ __launch_bounds__(256) void gcn_gather_linear(
    const unsigned int* __restrict__ fb32, const int* __restrict__ offs,
    const int* __restrict__ deg, const int* __restrict__ csr_src,
    const float* __restrict__ W, const float* __restrict__ b,
    float* __restrict__ out) {
    __shared__ float Ws[64][65];
    __shared__ float rowbuf[4][64];
    int tid = threadIdx.x;
    for (int i = tid; i < 64 * 64; i += 256)
        Ws[i >> 6][i & 63] = W[i];

    int wv = tid >> 6, lane = tid & 63;
    int sub = lane >> 5;        // which edge of the pair
    int k2 = lane & 31;         // u32 index within a feature row (2 feats)
    int node = blockIdx.x * 4 + wv;
    float accx = 0.0f, accy = 0.0f;
    if (node < N_NODES) {
        int start = offs[node];
        int d = deg[node];
        for (int base = 0; base < d; base += 64) {
            int cnt = min(64, d - base);
            int s = (base + lane < d) ? csr_src[start + base + lane] : 0;
            int j = 0;
            for (; j + 8 <= cnt; j += 8) {  // 4 pairs in flight
                int e0 = __shfl(s, j + sub);
                int e1 = __shfl(s, j + 2 + sub);
                int e2 = __shfl(s, j + 4 + sub);
                int e3 = __shfl(s, j + 6 + sub);
                unsigned int w0 = fb32[e0 * 32 + k2];
                unsigned int w1 = fb32[e1 * 32 + k2];
                unsigned int w2 = fb32[e2 * 32 + k2];
                unsigned int w3 = fb32[e3 * 32 + k2];
                accx += __uint_as_float(w0 << 16);
                accy += __uint_as_float(w0 & 0xffff0000u);
                accx += __uint_as_float(w1 << 16);
                accy += __uint_as_float(w1 & 0xffff0000u);
                accx += __uint_as_float(w2 << 16);
                accy += __uint_as_float(w2 & 0xffff0000u);
                accx += __uint_as_float(w3 << 16);
                accy += __uint_as_float(w3 & 0xffff0000u);
            }
            for (; j < cnt; j += 2) {
                int jj = j + sub;
                bool v = jj < cnt;
                int e = __shfl(s, v ? jj : j);
                unsigned int w = v ? fb32[e * 32 + k2] : 0u;
                accx += __uint_as_float(w << 16);
                accy += __uint_as_float(w & 0xffff0000u);
            }
        }
    }
    // cross-add the two edge-halves; lanes 0..31 then hold the full row
    accx += __shfl_xor(accx, 32);
    accy += __shfl_xor(accy, 32);
    if (lane < 32) {
        rowbuf[wv][2 * k2]     = accx;
        rowbuf[wv][2 * k2 + 1] = accy;
    }
    __syncthreads();  // also covers Ws staging
    if (node < N_NODES) {
        float sum = b[lane];
#pragma unroll
        for (int i = 0; i < FEATS; ++i)
            sum += Ws[lane][i] * rowbuf[wv][i];  // rowbuf read is broadcast
        out[node * FEATS + lane] = fmaxf(sum, 0.0f);
    }
}

extern "C" void kernel_launch(void* const* d_in, const int* in_sizes, int n_in,
                              void* d_out, int out_size, void* d_ws, size_t ws_size,
                              hipStream_t stream) {
    const float* features = (const float*)d_in[0];
    const int*   src      = (const int*)d_in[1];
    const int*   dst      = (const int*)d_in[2];
    const float* W        = (const float*)d_in[3];
    const float* b        = (const float*)d_in[4];
    float* out = (float*)d_out;

    // Workspace (ints): deg | offs | cursor | bsums | csr | featb(bf16)
    int* ws   = (int*)d_ws;
    int* deg    = ws;
    int* offs   = ws + 100000;
    int* cursor = ws + 200000;
    int* bsums  = ws + 300000;
    int* csr    = ws + 301024;
    unsigned short* featb = (unsigned short*)(ws + 301024 + 1600000);

    hipMemsetAsync(deg, 0, (size_t)N_NODES * sizeof(int), stream);

    gcn_tobf16<<<(N_NODES * FEATS / 4 + 255) / 256, 256, 0, stream>>>(
        features, (ushort4*)featb);
    gcn_hist<<<NCHUNK * NPART, 256, 0, stream>>>(dst, deg);
    gcn_scan_local<<<N_SCAN_BLOCKS, SCAN_B, 0, stream>>>(deg, offs, bsums);
    gcn_scan_bsums<<<1, 64, 0, stream>>>(bsums);
    gcn_scan_add<<<N_SCAN_BLOCKS, SCAN_B, 0, stream>>>(offs, bsums, cursor);
    gcn_fill<<<NCHUNK * NPART, 256, 0, stream>>>(src, dst, cursor, csr);

    gcn_gather_linear<<<(N_NODES + 3) / 4, 256, 0, stream>>>(
        (const unsigned int*)featb, offs, deg, csr, W, b, out);
}

// Round 6
// 218.108 us; speedup vs baseline: 1.9790x; 1.1549x over previous
//
#include <hip/hip_runtime.h>

#define N_NODES 100000
#define N_EDGES 1600000
#define FEATS 64
#define TILES 6250           // 100000/16 exact

#define NPART 8
#define NPP 12500            // nodes per partition
#define EPB 2048             // edges scanned per block chunk
#define NCHUNK ((N_EDGES + EPB - 1) / EPB)   // 782

#define SCAN_B 1024
#define N_SCAN_BLOCKS ((N_NODES + SCAN_B - 1) / SCAN_B)  // 98

typedef __attribute__((ext_vector_type(8))) short short8;   // 8 bf16 = 4 VGPR
typedef __attribute__((ext_vector_type(4))) float f32x4;

static __device__ __forceinline__ unsigned short f2bf(float f) {
    unsigned int u = __float_as_uint(f);
    unsigned int r = (u + 0x7fffu + ((u >> 16) & 1u)) >> 16;  // RNE
    return (unsigned short)r;
}
static __device__ __forceinline__ float bfl(unsigned int u) {
    return __uint_as_float(u << 16);
}
static __device__ __forceinline__ float bfh(unsigned int u) {
    return __uint_as_float(u & 0xffff0000u);
}

// g = bf16(feat @ W^T). MFMA 16x16x32 bf16. A and B fragments use the SAME
// k-index formula (k = 32*s + (lane>>4)*8 + j), so even if the HW k-mapping
// is a permutation of this, A and B permute identically and the contraction
// is unchanged. m/n = lane&15; C/D: col=lane&15, row=(lane>>4)*4+reg (m89).
// Each wave: 4 M-tiles of 16 rows x full N=64 (4 n-tiles), K=64 (2 k-steps).
__global__ __launch_bounds__(256) void gcn_gemm(
    const float* __restrict__ feat, const float* __restrict__ W,
    unsigned int* __restrict__ g32) {
    int l = threadIdx.x & 63, wv = threadIdx.x >> 6;
    int r = l & 15, c = l >> 4;

    // B frags: B[k][n] = W[n][k], n = 16t + r, k = 32s + c*8 + j
    short8 bf[4][2];
#pragma unroll
    for (int t = 0; t < 4; ++t)
#pragma unroll
        for (int s = 0; s < 2; ++s) {
            const float* wp = W + (16 * t + r) * 64 + 32 * s + c * 8;
            float4 w0 = *(const float4*)wp;
            float4 w1 = *(const float4*)(wp + 4);
            short8 f;
            f[0] = (short)f2bf(w0.x); f[1] = (short)f2bf(w0.y);
            f[2] = (short)f2bf(w0.z); f[3] = (short)f2bf(w0.w);
            f[4] = (short)f2bf(w1.x); f[5] = (short)f2bf(w1.y);
            f[6] = (short)f2bf(w1.z); f[7] = (short)f2bf(w1.w);
            bf[t][s] = f;
        }

    int tile0 = (blockIdx.x * 4 + wv) * 4;
#pragma unroll
    for (int ti = 0; ti < 4; ++ti) {
        int tile = tile0 + ti;
        if (tile >= TILES) break;   // wave-uniform
        int m0 = tile * 16;
        f32x4 acc0 = {0,0,0,0}, acc1 = {0,0,0,0}, acc2 = {0,0,0,0}, acc3 = {0,0,0,0};
#pragma unroll
        for (int s = 0; s < 2; ++s) {
            const float* ap = feat + (m0 + r) * 64 + 32 * s + c * 8;
            float4 a0 = *(const float4*)ap;
            float4 a1 = *(const float4*)(ap + 4);
            short8 af;
            af[0] = (short)f2bf(a0.x); af[1] = (short)f2bf(a0.y);
            af[2] = (short)f2bf(a0.z); af[3] = (short)f2bf(a0.w);
            af[4] = (short)f2bf(a1.x); af[5] = (short)f2bf(a1.y);
            af[6] = (short)f2bf(a1.z); af[7] = (short)f2bf(a1.w);
            acc0 = __builtin_amdgcn_mfma_f32_16x16x32_bf16(af, bf[0][s], acc0, 0, 0, 0);
            acc1 = __builtin_amdgcn_mfma_f32_16x16x32_bf16(af, bf[1][s], acc1, 0, 0, 0);
            acc2 = __builtin_amdgcn_mfma_f32_16x16x32_bf16(af, bf[2][s], acc2, 0, 0, 0);
            acc3 = __builtin_amdgcn_mfma_f32_16x16x32_bf16(af, bf[3][s], acc3, 0, 0, 0);
        }
        // Pack bf16 pairs across n (lanes l, l^1 share m) and store u32.
#pragma unroll
        for (int t = 0; t < 4; ++t) {
            f32x4 a = (t == 0) ? acc0 : (t == 1) ? acc1 : (t == 2) ? acc2 : acc3;
#pragma unroll
            for (int reg = 0; reg < 4; ++reg) {
                float d = a[reg];
                float o = __shfl_xor(d, 1);
                if (!(l & 1)) {
                    int m = m0 + c * 4 + reg;
                    int n = 16 * t + r;   // even
                    g32[(m * 64 + n) >> 1] =
                        (unsigned int)f2bf(d) | ((unsigned int)f2bf(o) << 16);
                }
            }
        }
    }
}

// ---- CSR build (unchanged from round 5; XCD-partitioned) ----

__global__ void gcn_hist(const int* __restrict__ dst, int* __restrict__ deg) {
    int part = blockIdx.x & (NPART - 1);
    int cb = (blockIdx.x >> 3) * EPB;
    int lo = part * NPP;
    for (int it = 0; it < EPB; it += 256) {
        int i = cb + it + threadIdx.x;
        if (i < N_EDGES) {
            unsigned int d = (unsigned int)(dst[i] - lo);
            if (d < NPP) atomicAdd(&deg[lo + d], 1);
        }
    }
}

__global__ void gcn_scan_local(const int* __restrict__ deg, int* __restrict__ offs,
                               int* __restrict__ bsums) {
    __shared__ int tmp[SCAN_B];
    int gid = blockIdx.x * SCAN_B + threadIdx.x;
    int v = (gid < N_NODES) ? deg[gid] : 0;
    tmp[threadIdx.x] = v;
    __syncthreads();
    for (int off = 1; off < SCAN_B; off <<= 1) {
        int t = (threadIdx.x >= off) ? tmp[threadIdx.x - off] : 0;
        __syncthreads();
        tmp[threadIdx.x] += t;
        __syncthreads();
    }
    if (gid < N_NODES) offs[gid] = tmp[threadIdx.x] - v;
    if (threadIdx.x == SCAN_B - 1) bsums[blockIdx.x] = tmp[threadIdx.x];
}

__global__ void gcn_scan_bsums(int* __restrict__ bsums) {
    int l = threadIdx.x;
    int a = 0, b = 0;
    if (2 * l < N_SCAN_BLOCKS)     a = bsums[2 * l];
    if (2 * l + 1 < N_SCAN_BLOCKS) b = bsums[2 * l + 1];
    int s = a + b;
    for (int off = 1; off < 64; off <<= 1) {
        int t = __shfl_up(s, off);
        if (l >= off) s += t;
    }
    int excl = s - (a + b);
    if (2 * l < N_SCAN_BLOCKS)     bsums[2 * l] = excl;
    if (2 * l + 1 < N_SCAN_BLOCKS) bsums[2 * l + 1] = excl + a;
}

__global__ void gcn_scan_add(int* __restrict__ offs, const int* __restrict__ bsums,
                             int* __restrict__ cursor) {
    int gid = blockIdx.x * SCAN_B + threadIdx.x;
    if (gid < N_NODES) {
        int o = offs[gid] + bsums[blockIdx.x];
        offs[gid] = o;
        cursor[gid] = o;
    }
}

__global__ void gcn_fill(const int* __restrict__ src, const int* __restrict__ dst,
                         int* __restrict__ cursor, int* __restrict__ csr) {
    int part = blockIdx.x & (NPART - 1);
    int cb = (blockIdx.x >> 3) * EPB;
    int lo = part * NPP;
    for (int it = 0; it < EPB; it += 256) {
        int i = cb + it + threadIdx.x;
        if (i < N_EDGES) {
            int d = dst[i];
            int s = src[i];
            if ((unsigned int)(d - lo) < NPP) {
                int slot = atomicAdd(&cursor[d], 1);
                csr[slot] = s;
            }
        }
    }
}

// ---- gather of transformed rows + bias + relu ----
// One wave per node. 4 sub-groups of 16 lanes; each sub-group reads one
// edge's full 128B bf16 row per dwordx2 step (1 cache line per edge).
// Lane (sub=l>>4, k=l&15) accumulates feats 4k..4k+3; two shfl_xor stages
// combine sub-groups; lanes 0..15 add bias, relu, store float4 (256B row).
__global__ __launch_bounds__(256) void gcn_gather(
    const uint2* __restrict__ g64, const int* __restrict__ offs,
    const int* __restrict__ deg, const int* __restrict__ csr,
    const float* __restrict__ bias, float* __restrict__ out) {
    int tid = threadIdx.x;
    int wv = tid >> 6, l = tid & 63;
    int node = blockIdx.x * 4 + wv;
    if (node >= N_NODES) return;
    int sub = l >> 4, k = l & 15;

    float a0 = 0.f, a1 = 0.f, a2 = 0.f, a3 = 0.f;
    int start = offs[node];
    int d = deg[node];
    for (int base = 0; base < d; base += 64) {
        int cnt = min(64, d - base);
        int s = (base + l < d) ? csr[start + base + l] : 0;
        int j = 0;
        for (; j + 8 <= cnt; j += 8) {
            int eA = __shfl(s, j + sub);
            int eB = __shfl(s, j + 4 + sub);
            uint2 wA = g64[eA * 16 + k];
            uint2 wB = g64[eB * 16 + k];
            a0 += bfl(wA.x); a1 += bfh(wA.x); a2 += bfl(wA.y); a3 += bfh(wA.y);
            a0 += bfl(wB.x); a1 += bfh(wB.x); a2 += bfl(wB.y); a3 += bfh(wB.y);
        }
        for (; j < cnt; j += 4) {
            int jj = j + sub;
            bool v = jj < cnt;
            int e = __shfl(s, v ? jj : 0);
            uint2 w = v ? g64[e * 16 + k] : make_uint2(0u, 0u);
            a0 += bfl(w.x); a1 += bfh(w.x); a2 += bfl(w.y); a3 += bfh(w.y);
        }
    }
    a0 += __shfl_xor(a0, 16); a0 += __shfl_xor(a0, 32);
    a1 += __shfl_xor(a1, 16); a1 += __shfl_xor(a1, 32);
    a2 += __shfl_xor(a2, 16); a2 += __shfl_xor(a2, 32);
    a3 += __shfl_xor(a3, 16); a3 += __shfl_xor(a3, 32);
    if (l < 16) {
        float4 b4 = *(const float4*)(bias + 4 * l);
        float4 o;
        o.x = fmaxf(a0 + b4.x, 0.0f);
        o.y = fmaxf(a1 + b4.y, 0.0f);
        o.z = fmaxf(a2 + b4.z, 0.0f);
        o.w = fmaxf(a3 + b4.w, 0.0f);
        *(float4*)(out + node * 64 + 4 * l) = o;
    }
}

extern "C" void kernel_launch(void* const* d_in, const int* in_sizes, int n_in,
                              void* d_out, int out_size, void* d_ws, size_t ws_size,
                              hipStream_t stream) {
    const float* features = (const float*)d_in[0];
    const int*   src      = (const int*)d_in[1];
    const int*   dst      = (const int*)d_in[2];
    const float* W        = (const float*)d_in[3];
    const float* b        = (const float*)d_in[4];
    float* out = (float*)d_out;

    // Workspace (ints): deg | offs | cursor | bsums | csr | g(bf16, 12.8MB)
    int* ws   = (int*)d_ws;
    int* deg    = ws;
    int* offs   = ws + 100000;
    int* cursor = ws + 200000;
    int* bsums  = ws + 300000;
    int* csr    = ws + 301024;
    unsigned int* g32 = (unsigned int*)(ws + 301024 + 1600000);  // 8B-aligned

    hipMemsetAsync(deg, 0, (size_t)N_NODES * sizeof(int), stream);

    // Transform first: g = bf16(feat @ W^T). 391 blocks x 4 waves x 4 tiles.
    gcn_gemm<<<(TILES + 15) / 16, 256, 0, stream>>>(features, W, g32);

    gcn_hist<<<NCHUNK * NPART, 256, 0, stream>>>(dst, deg);
    gcn_scan_local<<<N_SCAN_BLOCKS, SCAN_B, 0, stream>>>(deg, offs, bsums);
    gcn_scan_bsums<<<1, 64, 0, stream>>>(bsums);
    gcn_scan_add<<<N_SCAN_BLOCKS, SCAN_B, 0, stream>>>(offs, bsums, cursor);
    gcn_fill<<<NCHUNK * NPART, 256, 0, stream>>>(src, dst, cursor, csr);

    gcn_gather<<<(N_NODES + 3) / 4, 256, 0, stream>>>(
        (const uint2*)g32, offs, deg, csr, b, out);
}